// Round 1
// baseline (202.060 us; speedup 1.0000x reference)
//
#include <hip/hip_runtime.h>
#include <hip/hip_bf16.h>
#include <stdint.h>

#define Bb 8
#define Cc 128
#define Hh 96
#define Ww 160
#define HW (Hh*Ww)         // 15360
#define Kk 81

typedef __attribute__((ext_vector_type(8))) short short8;
typedef __attribute__((ext_vector_type(4))) float floatx4;
typedef __attribute__((ext_vector_type(4))) unsigned int uintx4;

__device__ __forceinline__ uint32_t bf16rne(float f) {
  uint32_t u = __float_as_uint(f);
  return (u + 0x7FFFu + ((u >> 16) & 1u)) >> 16;
}

// Block: 512 threads = 8 waves. Pixel region: 8 h x 16 w.
// Wave wv: vy = wv&3 (rows h0+2vy, h0+2vy+1), vx = wv>>2 (w0+8vx .. +7).
// MFMA 16x16x32 bf16: A = x2 (m = q-w index, 16 wide), B = x1 (n = p index:
// s=n>>3 selects h-row, pw=n&7), K = 32-channel chunk. C[m=q][n=p].
// LDS pixel record: 32 bf16 channels + 8 pad = 40 ushorts (80 B: 16B-aligned
// ds_read_b128, 20-bank stride -> only free 2-way conflicts).

__global__ __launch_bounds__(512, 2)
void corr_kernel(const float* __restrict__ x1, const float* __restrict__ x2,
                 float* __restrict__ out) {
  __shared__ __align__(16) ushort ldsX2[16*24*40];  // 30720 B
  __shared__ __align__(16) ushort ldsX1[8*16*40];   // 10240 B

  const int tid = threadIdx.x;
  const int w0 = blockIdx.x * 16;
  const int h0 = blockIdx.y * 8;
  const int b  = blockIdx.z;

  const int lane = tid & 63;
  const int wv   = tid >> 6;
  const int vy = wv & 3, vx = wv >> 2;
  const int n = lane & 15, quad = lane >> 4;
  const int s = n >> 3, pw = n & 7;

  floatx4 acc[10];
#pragma unroll
  for (int t = 0; t < 10; ++t) acc[t] = (floatx4){0.f, 0.f, 0.f, 0.f};

  for (int ck = 0; ck < 4; ++ck) {
    const int c0 = ck * 32;
    if (ck) __syncthreads();   // protect LDS reuse from previous chunk

    // ---- stage x2: 16 rows x 24 w x 4 cgroups(8ch) = 1536 tasks ----
#pragma unroll
    for (int it = 0; it < 3; ++it) {
      int T   = it * 512 + tid;
      int w24 = T % 24;
      int t2  = T / 24;        // 0..63
      int rw  = t2 & 15;
      int cg  = t2 >> 4;       // 0..3
      int gh = h0 - 4 + rw;
      int gw = w0 - 4 + w24;
      bool ok = ((unsigned)gh < Hh) && ((unsigned)gw < Ww);
      const float* src = x2 + ((size_t)(b*Cc + c0 + cg*8) * HW + gh*Ww + gw);
      uint32_t p0, p1, p2, p3;
      {
        float a0 = ok ? src[0*HW] : 0.f;
        float a1 = ok ? src[1*HW] : 0.f;
        float a2 = ok ? src[2*HW] : 0.f;
        float a3 = ok ? src[3*HW] : 0.f;
        float a4 = ok ? src[4*HW] : 0.f;
        float a5 = ok ? src[5*HW] : 0.f;
        float a6 = ok ? src[6*HW] : 0.f;
        float a7 = ok ? src[7*HW] : 0.f;
        p0 = bf16rne(a0) | (bf16rne(a1) << 16);
        p1 = bf16rne(a2) | (bf16rne(a3) << 16);
        p2 = bf16rne(a4) | (bf16rne(a5) << 16);
        p3 = bf16rne(a6) | (bf16rne(a7) << 16);
      }
      *(uintx4*)&ldsX2[(rw*24 + w24)*40 + cg*8] = (uintx4){p0, p1, p2, p3};
    }

    // ---- stage x1: 8 rows x 16 w x 4 cgroups = 512 tasks (1/thread) ----
    {
      int T  = tid;
      int wl = T & 15;
      int t2 = T >> 4;         // 0..31
      int rl = t2 & 7;
      int cg = t2 >> 3;        // 0..3
      const float* src = x1 + ((size_t)(b*Cc + c0 + cg*8) * HW
                               + (h0 + rl)*Ww + (w0 + wl));
      uint32_t p0, p1, p2, p3;
      float a0 = src[0*HW], a1 = src[1*HW], a2 = src[2*HW], a3 = src[3*HW];
      float a4 = src[4*HW], a5 = src[5*HW], a6 = src[6*HW], a7 = src[7*HW];
      p0 = bf16rne(a0) | (bf16rne(a1) << 16);
      p1 = bf16rne(a2) | (bf16rne(a3) << 16);
      p2 = bf16rne(a4) | (bf16rne(a5) << 16);
      p3 = bf16rne(a6) | (bf16rne(a7) << 16);
      *(uintx4*)&ldsX1[(rl*16 + wl)*40 + cg*8] = (uintx4){p0, p1, p2, p3};
    }

    __syncthreads();

    // ---- compute: B frag once, 10 q-rows of A ----
    short8 bfrag = *(const short8*)&ldsX1[((2*vy + s)*16 + 8*vx + pw)*40 + quad*8];
#pragma unroll
    for (int t = 0; t < 10; ++t) {
      short8 afrag = *(const short8*)&ldsX2[((2*vy + t)*24 + 8*vx + n)*40 + quad*8];
      acc[t] = __builtin_amdgcn_mfma_f32_16x16x32_bf16(afrag, bfrag, acc[t], 0, 0, 0);
    }
  }

  // ---- epilogue: scatter valid (di,dj) entries ----
  const float scale = 1.0f / 128.0f;
  const int ph  = h0 + 2*vy + s;
  const int pwg = w0 + 8*vx + pw;
#pragma unroll
  for (int t = 0; t < 10; ++t) {
    int di = t - 4 - s;
    if ((unsigned)(di + 4) > 8u) continue;
#pragma unroll
    for (int r = 0; r < 4; ++r) {
      int dj = quad*4 + r - 4 - pw;   // qw - pw
      if ((unsigned)(dj + 4) > 8u) continue;
      int kk = (di + 4) * 9 + (dj + 4);
      out[((size_t)b*Kk + kk) * HW + ph*Ww + pwg] = acc[t][r] * scale;
    }
  }
}

extern "C" void kernel_launch(void* const* d_in, const int* in_sizes, int n_in,
                              void* d_out, int out_size, void* d_ws, size_t ws_size,
                              hipStream_t stream) {
  const float* x1 = (const float*)d_in[0];
  const float* x2 = (const float*)d_in[1];
  float* out = (float*)d_out;
  dim3 grid(Ww/16, Hh/8, Bb);   // 10 x 12 x 8 = 960 blocks
  corr_kernel<<<grid, dim3(512, 1, 1), 0, stream>>>(x1, x2, out);
}